// Round 2
// baseline (4690.277 us; speedup 1.0000x reference)
//
#include <hip/hip_runtime.h>
#include <stdint.h>

#define V 4096
#define D 128
#define E 12288
#define NPAD 16384
#define HALF 8192
#define TARGET 2048
#define MAXM (V - TARGET)    // 2048 max merges
#define ROWU32 256           // 4096 fields * 2 bits = 256 u32 per row (1 KB)
#define CAP 16               // max accepts per round
#define NS 48                // row-cache slots (1 KB each) -> 48 KB

// s_waitcnt imms (gfx9): bits 3:0 vmcnt lo, 6:4 expcnt, 11:8 lgkmcnt, 15:14 vmcnt hi
#define WAIT_VM0   0x0F70    // vmcnt(0) only

// ws layout (bytes)
#define WS_N      0u                            // V*ROWU32*4 = 4 MB (2-bit matrix)
#define WS_PRI    (V * ROWU32 * 4u)             // V float
#define WS_KEYS   (WS_PRI + V * 4u)             // NPAD u64
#define WS_PK     (WS_KEYS + NPAD * 8u)         // E u32 (sorted packed edges)
#define WS_PAIRS  (WS_PK + E * 4u)              // MAXM u32
#define WS_MCOUNT (WS_PAIRS + MAXM * 4u)        // 1 int
#define WS_ALIVE  (WS_MCOUNT + 16u)             // V u8

typedef const __attribute__((address_space(1))) unsigned* gas1_t;
typedef __attribute__((address_space(3))) unsigned* las3_t;

__device__ __forceinline__ unsigned getf(const uint4& r, int c) {
    unsigned lo = (c & 2) ? r.z : r.x;
    unsigned hi = (c & 2) ? r.w : r.y;
    return (c & 1) ? hi : lo;
}
__device__ __forceinline__ void andf(uint4& r, int c, unsigned msk) {
    if (c == 0) r.x &= msk; else if (c == 1) r.y &= msk;
    else if (c == 2) r.z &= msk; else r.w &= msk;
}

__global__ void k_scatter(const int* __restrict__ edges, unsigned* __restrict__ n32) {
    int e = blockIdx.x * 256 + threadIdx.x;
    if (e < E) {
        int a = edges[e], b = edges[E + e];
        atomicOr(&n32[a * ROWU32 + (b >> 4)], 2u << ((b & 15) * 2));
        atomicOr(&n32[b * ROWU32 + (a >> 4)], 2u << ((a & 15) * 2));
    }
}

// numpy pairwise f32 sum for n=128 (matches np oracle reduction order)
__global__ void k_pri(const float* __restrict__ f, float* __restrict__ pri) {
    int v = blockIdx.x * 256 + threadIdx.x;
    if (v < V) {
        const float* p = f + v * D;
        float r[8];
#pragma unroll
        for (int j = 0; j < 8; j++) r[j] = __fmul_rn(p[j], p[j]);
        for (int i = 8; i < D; i += 8) {
#pragma unroll
            for (int j = 0; j < 8; j++)
                r[j] = __fadd_rn(r[j], __fmul_rn(p[i + j], p[i + j]));
        }
        float s01 = __fadd_rn(r[0], r[1]);
        float s23 = __fadd_rn(r[2], r[3]);
        float s45 = __fadd_rn(r[4], r[5]);
        float s67 = __fadd_rn(r[6], r[7]);
        pri[v] = __fadd_rn(__fadd_rn(s01, s23), __fadd_rn(s45, s67));
    }
}

__global__ void k_keys(const int* __restrict__ edges, const float* __restrict__ pri,
                       unsigned long long* __restrict__ keys) {
    int s = blockIdx.x * 256 + threadIdx.x;
    if (s < NPAD) {
        unsigned long long rec;
        if (s < E) {
            int a = edges[s], b = edges[E + s];
            float k = __fadd_rn(pri[a], pri[b]);   // epri >= 0 -> bits monotone
            rec = ((unsigned long long)__float_as_uint(k) << 32) | (unsigned)s;
        } else {
            rec = (0xFFFFFFFFull << 32) | (unsigned)s;
        }
        keys[s] = rec;
    }
}

// bitonic sort one 8192-element half in LDS; 2 blocks run concurrently
__launch_bounds__(1024)
__global__ void k_sort2(unsigned long long* __restrict__ keys) {
    __shared__ unsigned long long srt[HALF];
    const int tid = threadIdx.x;
    unsigned long long* base = keys + blockIdx.x * HALF;
    for (int s = tid; s < HALF; s += 1024) srt[s] = base[s];
    __syncthreads();
    for (int k = 2; k <= HALF; k <<= 1) {
        for (int j = k >> 1; j >= 1; j >>= 1) {
            for (int i = tid; i < HALF; i += 1024) {
                int ixj = i ^ j;
                if (ixj > i) {
                    unsigned long long x = srt[i], y = srt[ixj];
                    bool up = ((i & k) == 0);
                    if ((x > y) == up) { srt[i] = y; srt[ixj] = x; }
                }
            }
            __syncthreads();
        }
    }
    for (int s = tid; s < HALF; s += 1024) base[s] = srt[s];
}

// merge-path the two sorted halves; emit packed (v0<<16|v1) in global order
__launch_bounds__(64)
__global__ void k_mergepath(const unsigned long long* __restrict__ keys,
                            const int* __restrict__ edges, unsigned* __restrict__ pkG) {
    int t = blockIdx.x * 64 + threadIdx.x;
    if (t >= E / 64) return;
    const unsigned long long* A = keys;
    const unsigned long long* B = keys + HALF;
    int d = t * 64;
    int lo = d > HALF ? d - HALF : 0;
    int hi = d < HALF ? d : HALF;
    while (lo < hi) {
        int mid = (lo + hi) >> 1;
        if (A[mid] < B[d - 1 - mid]) lo = mid + 1; else hi = mid;
    }
    int ia = lo, ib = d - lo;
    for (int o = d; o < d + 64; o++) {
        bool takeA = (ib >= HALF) || (ia < HALF && A[ia] < B[ib]);
        unsigned long long r = takeA ? A[ia++] : B[ib++];
        int e = (int)(r & 0xFFFFFFFFull);
        int a = edges[e], b = edges[E + e];
        pkG[o] = ((unsigned)a << 16) | (unsigned)b;
    }
}

// ONE wave: windowed monotone scan + coherent write-through row cache.
// This revision: (1) register/shfl-based slot ASSIGN (no LDS dedupe chain,
// no LDS atomics); (2) DEAD refinement in the greedy keep -- a candidate whose
// endpoint equals a KEPT earlier candidate's dying vertex is definitively dead
// and no longer blocks later candidates, breaking serial conflict chains.
__launch_bounds__(64, 1)
__global__ void k_collapse(const unsigned* __restrict__ pkG, unsigned* n32,
                           unsigned* __restrict__ pairsG, int* __restrict__ mcountG,
                           uint8_t* __restrict__ aliveG, float* __restrict__ out) {
    __shared__ unsigned shRows[NS * ROWU32];        // 48 KB row cache
    __shared__ uint8_t  alive[V];                   // 4 KB
    __shared__ uint8_t  shV2S[V];                   // 4 KB vertex -> slot hint
    __shared__ unsigned shSlotV[NS];                // slot -> vertex (0xFFFFFFFF free)
    __shared__ unsigned shCand[CAP];
    __shared__ unsigned shConf[CAP];                // conflict mask (bits j<k)
    __shared__ unsigned shDeadM[CAP];               // "j's v1 kills k" mask
    __shared__ uint8_t  shCS[2 * CAP];              // candidate endpoint -> slot
    __shared__ unsigned shFetch[2 * CAP];           // (slot<<16)|vertex fetch list
    const int lane = threadIdx.x;
    for (int v = lane; v < V; v += 64) { alive[v] = 1; shV2S[v] = 0xFF; }
    if (lane < NS) shSlotV[lane] = 0xFFFFFFFFu;
    __syncthreads();

    int cnt = V, mcount = 0;
    bool done = false;

    for (int w = 0; w < E && !done; w += 64) {
        unsigned pkv = pkG[w + lane];                // pkG is never written here
        const int a = (int)(pkv >> 16), b = (int)(pkv & 0xFFFFu);
        bool dec = !(alive[a] && alive[b]);          // monotone: false is final
        unsigned fv = 0u;
        bool needG = false;
        if (!dec) {
            int s = shV2S[a];
            if (s < NS && shSlotV[s] == (unsigned)a)
                fv = (shRows[s * ROWU32 + (b >> 4)] >> ((b & 15) * 2)) & 3u;
            else {
                s = shV2S[b];
                if (s < NS && shSlotV[s] == (unsigned)b)
                    fv = (shRows[s * ROWU32 + (a >> 4)] >> ((a & 15) * 2)) & 3u;
                else needG = true;
            }
        }
        if (__ballot(needG)) {                       // drain only if someone reads global
            __builtin_amdgcn_s_waitcnt(WAIT_VM0);
            if (needG) {
                unsigned wv = *(volatile unsigned*)(n32 + a * ROWU32 + (b >> 4));
                fv = (wv >> ((b & 15) * 2)) & 3u;
            }
        }

        while (!done) {
            if (!dec && fv != 2u) dec = true;         // monotone reject (final)
            unsigned long long mF = __ballot(!dec);   // undecided == flagged
            if (!mF) break;
            int limit = cnt - TARGET; if (limit > CAP) limit = CAP;
            int flagged = (int)__popcll(mF);
            int nacc = flagged < limit ? flagged : limit;

            // ---- SELECT: first nacc flagged lanes, post to LDS ----
            int myK = -1;
            if (!dec) {
                int rank = (int)__popcll(mF & ((1ull << lane) - 1ull));
                if (rank < limit) { myK = rank; shCand[rank] = pkv; }
            }
            if (lane < CAP) { shConf[lane] = 0u; shDeadM[lane] = 0u; }
            __syncthreads();

            // ---- ASSIGN: register/shfl-based (single wave: all LDS reads of
            // this phase are issued in program order before any of its writes)
            int ev = -1, slotHit = -1;
            const bool validE = (lane < 2 * nacc);
            if (validE) {
                unsigned cp = shCand[lane >> 1];
                ev = (lane & 1) ? (int)(cp & 0xFFFFu) : (int)(cp >> 16);
                int s = shV2S[ev];
                if (s < NS && shSlotV[s] == (unsigned)ev) slotHit = s;
            }
            // pinned-slot mask: wave OR-reduce of hit slots
            unsigned long long pin = (slotHit >= 0) ? (1ull << slotHit) : 0ull;
            for (int o = 32; o; o >>= 1) pin |= __shfl_xor(pin, o);
            // dedupe: leader = first entry with this vertex (register shuffle scan)
            unsigned key = validE ? (unsigned)ev : (0x10000u + (unsigned)lane);
            bool dupPrev = false;
            for (int q = 0; q < 32; q++) {
                unsigned kq = __shfl(key, q);
                if (q < lane && kq == key) dupPrev = true;
            }
            const bool leader = validE && slotHit < 0 && !dupPrev;
            unsigned long long mLead = __ballot(leader);
            int nf = (int)__popcll(mLead);
            if (leader) {
                int r = (int)__popcll(mLead & ((1ull << lane) - 1ull));
                unsigned long long freeM = ~pin & ((1ull << NS) - 1ull);
                for (int t = 0; t < r; t++) freeM &= freeM - 1ull;   // r-th free slot
                int slot = __ffsll(freeM) - 1;
                shSlotV[slot] = (unsigned)ev;        // evict (write-through: no writeback)
                shV2S[ev] = (uint8_t)slot;
                shCS[lane] = (uint8_t)slot;
                shFetch[r] = ((unsigned)slot << 16) | (unsigned)ev;
            } else if (slotHit >= 0) {
                shCS[lane] = (uint8_t)slotHit;
            }
            __syncthreads();
            if (validE && slotHit < 0 && dupPrev) shCS[lane] = shV2S[ev];

            // ---- FETCH only missing rows; skip both drains when all hit ----
            if (nf > 0) {
                __builtin_amdgcn_s_waitcnt(WAIT_VM0);        // prior fixup stores visible
                for (int f = 0; f < nf; f++) {
                    unsigned fe = shFetch[f];
                    int slot = (int)(fe >> 16), vv = (int)(fe & 0xFFFFu);
                    __builtin_amdgcn_global_load_lds(
                        (gas1_t)(n32 + vv * ROWU32 + lane * 4),
                        (las3_t)(shRows + slot * ROWU32), 16, 0, 0);
                }
                __builtin_amdgcn_s_waitcnt(WAIT_VM0);
            }
            __syncthreads();

            // ---- FILTER: pairwise (j<k) conflicts, <=4 pairs per lane ----
            for (int pp = lane; pp < CAP * CAP; pp += 64) {
                int k = pp >> 4, j = pp & 15;
                if (j < k && k < nacc) {
                    unsigned cj = shCand[j], ck = shCand[k];
                    int v0j = (int)(cj >> 16), v1j = (int)(cj & 0xFFFFu);
                    int v0k = (int)(ck >> 16), v1k = (int)(ck & 0xFFFFu);
                    // dkill: j's dying vertex is one of k's endpoints
                    bool dkill = (v0k == v1j) || (v1k == v1j);
                    // shared endpoints (exact order semantics + disjointness)
                    bool c = dkill || (v0k == v0j) || (v1k == v0j);
                    const unsigned* rBj = shRows + (int)shCS[2 * j + 1] * ROWU32;
                    const unsigned* rBk = shRows + (int)shCS[2 * k + 1] * ROWU32;
                    // H1: {v0k,v1k} adjacent to v1j
                    c |= ((rBj[v0k >> 4] >> ((v0k & 15) * 2)) & 3u) != 0u;
                    c |= ((rBj[v1k >> 4] >> ((v1k & 15) * 2)) & 3u) != 0u;
                    // H2: v0j adjacent to v1k
                    c |= ((rBk[v0j >> 4] >> ((v0j & 15) * 2)) & 3u) != 0u;
                    if (c) atomicOr(&shConf[k], 1u << j);
                    if (dkill) atomicOr(&shDeadM[k], 1u << j);
                }
            }
            __syncthreads();

            // ---- GREEDY keep (replicated, pure VALU) with DEAD refinement ----
            // kept: no conflict with kept|blocked. dead: endpoint killed by an
            // earlier KEPT merge (final; never blocks later candidates).
            unsigned kept = 0u, blocked = 0u, deadm = 0u;
            for (int k = 0; k < nacc; k++) {
                unsigned bit = 1u << k;
                if (shDeadM[k] & kept) { deadm |= bit; continue; }
                if (shConf[k] & (kept | blocked)) { blocked |= bit; continue; }
                kept |= bit;
            }
            int nk = __popc(kept);                   // >=1: k=0 has empty row
            if (myK >= 0 && (((kept | deadm) >> myK) & 1u)) dec = true;   // decided

            // ---- MARK: alive + merge log (priority order) ----
            if (lane < nacc && ((kept >> lane) & 1u)) {
                unsigned cp = shCand[lane];
                alive[(int)(cp & 0xFFFFu)] = 0;
                int r = __popc(kept & ((1u << lane) - 1u));
                pairsG[mcount + r] = cp;
            }
            mcount += nk; cnt -= nk;
            __syncthreads();

            // ---- APPLY: group g = lane>>2 applies kept candidate g ----
            {
                int g = lane >> 2, sub = lane & 3;
                if (g < nacc && ((kept >> g) & 1u)) {
                    unsigned cp = shCand[g];
                    int v0 = (int)(cp >> 16), v1 = (int)(cp & 0xFFFFu);
                    int sA = shCS[2 * g], sB = shCS[2 * g + 1];
                    uint4* rowA = (uint4*)(shRows + sA * ROWU32);
                    const uint4* rowB = (const uint4*)(shRows + sB * ROWU32);
                    if (sub == 0) shSlotV[sB] = 0xFFFFFFFFu;   // v1 dead: free its slot
                    int m0u = v0 >> 6, m1u = v1 >> 6;
                    int sh0 = (v0 & 15) * 2, wi0 = v0 >> 4;
                    for (int t = 0; t < 16; t++) {
                        int u = sub * 16 + ((t + lane) & 15);   // bank-spread rotation
                        uint4 ra = rowA[u], rb = rowB[u];
                        uint4 rr;
                        rr.x = ra.x | rb.x | ((ra.x & rb.x & 0xAAAAAAAAu) >> 1);
                        rr.y = ra.y | rb.y | ((ra.y & rb.y & 0xAAAAAAAAu) >> 1);
                        rr.z = ra.z | rb.z | ((ra.z & rb.z & 0xAAAAAAAAu) >> 1);
                        rr.w = ra.w | rb.w | ((ra.w & rb.w & 0xAAAAAAAAu) >> 1);
                        if (u == m0u) andf(rr, (v0 >> 4) & 3, ~(3u << ((v0 & 15) * 2)));
                        if (u == m1u) andf(rr, (v1 >> 4) & 3, ~(3u << ((v1 & 15) * 2)));
                        ((uint4*)(n32 + v0 * ROWU32))[u] = rr;  // write-through global
                        rowA[u] = rr;                            // in-place cache update
                        // column fixups: global atomicXor + cached-copy mirror
#pragma unroll
                        for (int c = 0; c < 4; c++) {
                            unsigned bb = getf(rb, c);
                            if (!bb) continue;
                            unsigned aa = getf(ra, c), vvv = getf(rr, c);
                            int xbase = (u << 6) + (c << 4);
                            unsigned tt = bb;
                            while (tt) {
                                int q = (__ffs(tt) - 1) >> 1;
                                tt &= ~(3u << (q * 2));
                                int x = xbase + q;
                                if (x != v0 && x != v1) {
                                    unsigned dx =
                                        (((aa >> (q*2)) ^ (vvv >> (q*2))) & 3u) << sh0;
                                    if (dx) {
                                        atomicXor(n32 + x * ROWU32 + wi0, dx);
                                        int sx = shV2S[x];
                                        if (sx < NS && shSlotV[sx] == (unsigned)x)
                                            atomicXor(&shRows[sx * ROWU32 + wi0], dx);
                                    }
                                }
                            }
                        }
                    }
                }
            }
            __syncthreads();

            // ---- REFRESH: any cached endpoint row gives the current field ----
            if (!dec) {
                if (!alive[a] || !alive[b]) dec = true;   // endpoint died (final)
                else {
                    int s = shV2S[a];
                    if (s < NS && shSlotV[s] == (unsigned)a)
                        fv = (shRows[s * ROWU32 + (b >> 4)] >> ((b & 15) * 2)) & 3u;
                    else {
                        s = shV2S[b];
                        if (s < NS && shSlotV[s] == (unsigned)b)
                            fv = (shRows[s * ROWU32 + (a >> 4)] >> ((a & 15) * 2)) & 3u;
                        // neither cached: fv unchanged — any change this round
                        // implies a kept-v0 endpoint, which is cache-resident.
                    }
                }
            }
            __syncthreads();

            if (cnt == TARGET) done = true;
        }
    }

    for (int v = lane; v < V; v += 64) {
        uint8_t ao = alive[v];
        aliveG[v] = ao;
        out[V * D + v] = ao ? 1.0f : 0.0f;
    }
    if (lane == 0) { mcountG[0] = mcount; out[V * D + V] = (float)cnt; }
}

// Replay merge forest: per-vertex (root, weight) then scatter-add w*f[v] into out[root].
__launch_bounds__(256)
__global__ void k_apply(const float* __restrict__ f, const unsigned* __restrict__ pairsG,
                        const int* __restrict__ mcountG, float* __restrict__ out) {
    __shared__ unsigned pl[MAXM];
    __shared__ int rootL[256];
    __shared__ float wL[256];
    const int tid = threadIdx.x;
    const int mc = mcountG[0];
    for (int j = tid; j < mc; j += 256) pl[j] = pairsG[j];
    __syncthreads();
    int cur = blockIdx.x * 256 + tid;
    float w = 1.0f;
    for (int j = 0; j < mc; j++) {
        unsigned p = pl[j];
        int v0 = (int)(p >> 16), v1 = (int)(p & 0xFFFFu);
        if (cur == v1) { cur = v0; w *= 0.5f; }
        else if (cur == v0) w *= 0.5f;
    }
    rootL[tid] = cur;
    wL[tid] = w;
    __syncthreads();
    const int sub = tid >> 7;
    const int d = tid & 127;
    for (int s = 0; s < 256; s += 2) {
        int idx = s + sub;
        int vv = blockIdx.x * 256 + idx;
        atomicAdd(&out[rootL[idx] * D + d], wL[idx] * f[vv * D + d]);
    }
}

extern "C" void kernel_launch(void* const* d_in, const int* in_sizes, int n_in,
                              void* d_out, int out_size, void* d_ws, size_t ws_size,
                              hipStream_t stream) {
    (void)in_sizes; (void)n_in; (void)out_size; (void)ws_size;
    const float* features = (const float*)d_in[0];
    const int* edges = (const int*)d_in[1];
    uint8_t* ws = (uint8_t*)d_ws;
    unsigned* n32 = (unsigned*)(ws + WS_N);
    float* pri = (float*)(ws + WS_PRI);
    unsigned long long* keys = (unsigned long long*)(ws + WS_KEYS);
    unsigned* pkG = (unsigned*)(ws + WS_PK);
    unsigned* pairsG = (unsigned*)(ws + WS_PAIRS);
    int* mcountG = (int*)(ws + WS_MCOUNT);
    uint8_t* aliveG = ws + WS_ALIVE;
    float* out = (float*)d_out;

    hipMemsetAsync(n32, 0, (size_t)V * ROWU32 * 4, stream);
    hipMemsetAsync(out, 0, (size_t)V * D * sizeof(float), stream);
    k_pri<<<(V + 255) / 256, 256, 0, stream>>>(features, pri);
    k_scatter<<<(E + 255) / 256, 256, 0, stream>>>(edges, n32);
    k_keys<<<(NPAD + 255) / 256, 256, 0, stream>>>(edges, pri, keys);
    k_sort2<<<2, 1024, 0, stream>>>(keys);
    k_mergepath<<<(E / 64 + 63) / 64, 64, 0, stream>>>(keys, edges, pkG);
    k_collapse<<<1, 64, 0, stream>>>(pkG, n32, pairsG, mcountG, aliveG, out);
    k_apply<<<V / 256, 256, 0, stream>>>(features, pairsG, mcountG, out);
}

// Round 3
// 3818.419 us; speedup vs baseline: 1.2283x; 1.2283x over previous
//
#include <hip/hip_runtime.h>
#include <stdint.h>

#define V 4096
#define D 128
#define E 12288
#define NPAD 16384
#define HALF 8192
#define TARGET 2048
#define MAXM (V - TARGET)    // 2048 max merges
#define ROWU32 256           // 4096 fields * 2 bits = 256 u32 per row (1 KB)
#define CAP 32               // max accepts per round (pool design)

// s_waitcnt imms (gfx9): bits 3:0 vmcnt lo, 6:4 expcnt, 11:8 lgkmcnt, 15:14 vmcnt hi
#define WAIT_VM0   0x0F70    // vmcnt(0) only

// ws layout (bytes)
#define WS_N      0u                            // V*ROWU32*4 = 4 MB (2-bit matrix)
#define WS_PRI    (V * ROWU32 * 4u)             // V float
#define WS_KEYS   (WS_PRI + V * 4u)             // NPAD u64
#define WS_PK     (WS_KEYS + NPAD * 8u)         // E u32 (sorted packed edges)
#define WS_PAIRS  (WS_PK + E * 4u)              // MAXM u32
#define WS_MCOUNT (WS_PAIRS + MAXM * 4u)        // 1 int
#define WS_ALIVE  (WS_MCOUNT + 16u)             // V u8

typedef const __attribute__((address_space(1))) unsigned* gas1_t;
typedef __attribute__((address_space(3))) unsigned* las3_t;

__device__ __forceinline__ unsigned getf(const uint4& r, int c) {
    unsigned lo = (c & 2) ? r.z : r.x;
    unsigned hi = (c & 2) ? r.w : r.y;
    return (c & 1) ? hi : lo;
}
__device__ __forceinline__ void andf(uint4& r, int c, unsigned msk) {
    if (c == 0) r.x &= msk; else if (c == 1) r.y &= msk;
    else if (c == 2) r.z &= msk; else r.w &= msk;
}

__global__ void k_scatter(const int* __restrict__ edges, unsigned* __restrict__ n32) {
    int e = blockIdx.x * 256 + threadIdx.x;
    if (e < E) {
        int a = edges[e], b = edges[E + e];
        atomicOr(&n32[a * ROWU32 + (b >> 4)], 2u << ((b & 15) * 2));
        atomicOr(&n32[b * ROWU32 + (a >> 4)], 2u << ((a & 15) * 2));
    }
}

// numpy pairwise f32 sum for n=128 (matches np oracle reduction order)
__global__ void k_pri(const float* __restrict__ f, float* __restrict__ pri) {
    int v = blockIdx.x * 256 + threadIdx.x;
    if (v < V) {
        const float* p = f + v * D;
        float r[8];
#pragma unroll
        for (int j = 0; j < 8; j++) r[j] = __fmul_rn(p[j], p[j]);
        for (int i = 8; i < D; i += 8) {
#pragma unroll
            for (int j = 0; j < 8; j++)
                r[j] = __fadd_rn(r[j], __fmul_rn(p[i + j], p[i + j]));
        }
        float s01 = __fadd_rn(r[0], r[1]);
        float s23 = __fadd_rn(r[2], r[3]);
        float s45 = __fadd_rn(r[4], r[5]);
        float s67 = __fadd_rn(r[6], r[7]);
        pri[v] = __fadd_rn(__fadd_rn(s01, s23), __fadd_rn(s45, s67));
    }
}

__global__ void k_keys(const int* __restrict__ edges, const float* __restrict__ pri,
                       unsigned long long* __restrict__ keys) {
    int s = blockIdx.x * 256 + threadIdx.x;
    if (s < NPAD) {
        unsigned long long rec;
        if (s < E) {
            int a = edges[s], b = edges[E + s];
            float k = __fadd_rn(pri[a], pri[b]);   // epri >= 0 -> bits monotone
            rec = ((unsigned long long)__float_as_uint(k) << 32) | (unsigned)s;
        } else {
            rec = (0xFFFFFFFFull << 32) | (unsigned)s;
        }
        keys[s] = rec;
    }
}

// bitonic sort one 8192-element half in LDS; 2 blocks run concurrently
__launch_bounds__(1024)
__global__ void k_sort2(unsigned long long* __restrict__ keys) {
    __shared__ unsigned long long srt[HALF];
    const int tid = threadIdx.x;
    unsigned long long* base = keys + blockIdx.x * HALF;
    for (int s = tid; s < HALF; s += 1024) srt[s] = base[s];
    __syncthreads();
    for (int k = 2; k <= HALF; k <<= 1) {
        for (int j = k >> 1; j >= 1; j >>= 1) {
            for (int i = tid; i < HALF; i += 1024) {
                int ixj = i ^ j;
                if (ixj > i) {
                    unsigned long long x = srt[i], y = srt[ixj];
                    bool up = ((i & k) == 0);
                    if ((x > y) == up) { srt[i] = y; srt[ixj] = x; }
                }
            }
            __syncthreads();
        }
    }
    for (int s = tid; s < HALF; s += 1024) base[s] = srt[s];
}

// merge-path the two sorted halves; emit packed (v0<<16|v1) in global order
__launch_bounds__(64)
__global__ void k_mergepath(const unsigned long long* __restrict__ keys,
                            const int* __restrict__ edges, unsigned* __restrict__ pkG) {
    int t = blockIdx.x * 64 + threadIdx.x;
    if (t >= E / 64) return;
    const unsigned long long* A = keys;
    const unsigned long long* B = keys + HALF;
    int d = t * 64;
    int lo = d > HALF ? d - HALF : 0;
    int hi = d < HALF ? d : HALF;
    while (lo < hi) {
        int mid = (lo + hi) >> 1;
        if (A[mid] < B[d - 1 - mid]) lo = mid + 1; else hi = mid;
    }
    int ia = lo, ib = d - lo;
    for (int o = d; o < d + 64; o++) {
        bool takeA = (ib >= HALF) || (ia < HALF && A[ia] < B[ib]);
        unsigned long long r = takeA ? A[ia++] : B[ib++];
        int e = (int)(r & 0xFFFFFFFFull);
        int a = edges[e], b = edges[E + e];
        pkG[o] = ((unsigned)a << 16) | (unsigned)b;
    }
}

// ONE wave: CANDIDATE-POOL monotone scan (replaces fixed 64-edge windows).
// Each lane holds one undecided candidate; after every round the undecided
// survivors are compacted to the low lanes (register shuffles, priority order
// preserved) and freed lanes refill from the sorted stream. The flagged set
// is thus always full -> nacc pinned at CAP instead of dwindling window tails.
// CAP=32 doubles the greedy independent-set horizon. No row cache (rows are
// L2-resident; LDS pointer-chases cost more than the L2 fetch they save).
__launch_bounds__(64, 1)
__global__ void k_collapse(const unsigned* __restrict__ pkG, unsigned* n32,
                           unsigned* __restrict__ pairsG, int* __restrict__ mcountG,
                           uint8_t* __restrict__ aliveG, float* __restrict__ out) {
    __shared__ unsigned shRows[2 * CAP * ROWU32];   // 64 KB: slot 2k=row v0, 2k+1=row v1
    __shared__ uint8_t  alive[V];                   // 4 KB
    __shared__ unsigned shCand[CAP];
    __shared__ unsigned shConf[CAP];                // conflict mask (bits j<k)
    __shared__ unsigned shDeadM[CAP];               // "j's v1 kills k" mask
    const int lane = threadIdx.x;
    for (int v = lane; v < V; v += 64) alive[v] = 1;
    __syncthreads();

    int cnt = V, mcount = 0, head = 64;
    // ---- pool state (one candidate per lane; lane order == priority order) ----
    unsigned pkv = pkG[lane];
    unsigned fv = 0u;
    bool fknown = false;
    bool dec = false;                               // decided-or-inactive

    while (true) {
        const int a = (int)(pkv >> 16), b = (int)(pkv & 0xFFFFu);
        // 1. alive check (monotone: dec==true is final)
        if (!dec && !(alive[a] && alive[b])) dec = true;
        // 2. resolve unknown fields (one drain covers prior round's stores)
        bool unk = !dec && !fknown;
        bool drained = false;
        if (__ballot(unk)) {
            __builtin_amdgcn_s_waitcnt(WAIT_VM0);
            drained = true;
            if (unk) {
                unsigned wv = *(volatile unsigned*)(n32 + a * ROWU32 + (b >> 4));
                fv = (wv >> ((b & 15) * 2)) & 3u;
                fknown = true;
            }
        }
        if (!dec && fv != 2u) dec = true;            // monotone reject (final)
        unsigned long long mF = __ballot(!dec);

        if (mF) {
            int limit = cnt - TARGET; if (limit > CAP) limit = CAP;
            int flagged = (int)__popcll(mF);
            int nacc = flagged < limit ? flagged : limit;

            // ---- SELECT: first nacc flagged lanes (= lowest priority index) ----
            int myK = -1;
            if (!dec) {
                int rank = (int)__popcll(mF & ((1ull << lane) - 1ull));
                if (rank < limit) { myK = rank; shCand[rank] = pkv; }
            }
            if (lane < CAP) { shConf[lane] = 0u; shDeadM[lane] = 0u; }
            __syncthreads();

            // ---- FETCH rows (fixed slots; drain prior stores if not yet) ----
            if (!drained) __builtin_amdgcn_s_waitcnt(WAIT_VM0);
            for (int k = 0; k < nacc; k++) {
                unsigned cp = shCand[k];
                int v0 = (int)(cp >> 16), v1 = (int)(cp & 0xFFFFu);
                __builtin_amdgcn_global_load_lds(
                    (gas1_t)(n32 + v0 * ROWU32 + lane * 4),
                    (las3_t)(shRows + (2 * k) * ROWU32), 16, 0, 0);
                __builtin_amdgcn_global_load_lds(
                    (gas1_t)(n32 + v1 * ROWU32 + lane * 4),
                    (las3_t)(shRows + (2 * k + 1) * ROWU32), 16, 0, 0);
            }
            __builtin_amdgcn_s_waitcnt(WAIT_VM0);
            __syncthreads();

            // ---- FILTER: pairwise (j<k) conflicts, 16 pairs per lane ----
            for (int pp = lane; pp < CAP * CAP; pp += 64) {
                int k = pp >> 5, j = pp & 31;
                if (j < k && k < nacc) {
                    unsigned cj = shCand[j], ck = shCand[k];
                    int v0j = (int)(cj >> 16), v1j = (int)(cj & 0xFFFFu);
                    int v0k = (int)(ck >> 16), v1k = (int)(ck & 0xFFFFu);
                    // dkill: j's dying vertex is one of k's endpoints
                    bool dkill = (v0k == v1j) || (v1k == v1j);
                    bool c = dkill || (v0k == v0j) || (v1k == v0j);
                    const unsigned* rBj = shRows + (2 * j + 1) * ROWU32;
                    const unsigned* rBk = shRows + (2 * k + 1) * ROWU32;
                    // H1: {v0k,v1k} adjacent to v1j
                    c |= ((rBj[v0k >> 4] >> ((v0k & 15) * 2)) & 3u) != 0u;
                    c |= ((rBj[v1k >> 4] >> ((v1k & 15) * 2)) & 3u) != 0u;
                    // H2: v0j adjacent to v1k
                    c |= ((rBk[v0j >> 4] >> ((v0j & 15) * 2)) & 3u) != 0u;
                    if (c) atomicOr(&shConf[k], 1u << j);
                    if (dkill) atomicOr(&shDeadM[k], 1u << j);
                }
            }
            __syncthreads();

            // ---- GREEDY keep (replicated VALU) with DEAD refinement ----
            unsigned kept = 0u, blocked = 0u, deadm = 0u;
            for (int k = 0; k < nacc; k++) {
                unsigned bit = 1u << k;
                if (shDeadM[k] & kept) { deadm |= bit; continue; }
                if (shConf[k] & (kept | blocked)) { blocked |= bit; continue; }
                kept |= bit;
            }
            int nk = __popc(kept);                   // >=1: k=0 has empty row
            if (myK >= 0 && (((kept | deadm) >> myK) & 1u)) dec = true;

            // ---- MARK: alive + merge log (priority order) ----
            if (lane < nacc && ((kept >> lane) & 1u)) {
                unsigned cp = shCand[lane];
                alive[(int)(cp & 0xFFFFu)] = 0;
                int r = __popc(kept & ((1u << lane) - 1u));
                pairsG[mcount + r] = cp;
            }
            mcount += nk; cnt -= nk;
            __syncthreads();
            if (cnt == TARGET) break;                // no future rounds: skip apply

            // ---- APPLY: group g = lane>>1 applies kept candidate g ----
            {
                int g = lane >> 1, sub = lane & 1;
                if (g < nacc && ((kept >> g) & 1u)) {
                    unsigned cp = shCand[g];
                    int v0 = (int)(cp >> 16), v1 = (int)(cp & 0xFFFFu);
                    const uint4* rowA = (const uint4*)(shRows + (2 * g) * ROWU32);
                    const uint4* rowB = (const uint4*)(shRows + (2 * g + 1) * ROWU32);
                    int m0u = v0 >> 6, m1u = v1 >> 6;
                    int sh0 = (v0 & 15) * 2, wi0 = v0 >> 4;
                    for (int t = 0; t < 32; t++) {
                        int u = sub * 32 + ((t + lane) & 31);   // bank-spread rotation
                        uint4 ra = rowA[u], rb = rowB[u];
                        uint4 rr;
                        rr.x = ra.x | rb.x | ((ra.x & rb.x & 0xAAAAAAAAu) >> 1);
                        rr.y = ra.y | rb.y | ((ra.y & rb.y & 0xAAAAAAAAu) >> 1);
                        rr.z = ra.z | rb.z | ((ra.z & rb.z & 0xAAAAAAAAu) >> 1);
                        rr.w = ra.w | rb.w | ((ra.w & rb.w & 0xAAAAAAAAu) >> 1);
                        if (u == m0u) andf(rr, (v0 >> 4) & 3, ~(3u << ((v0 & 15) * 2)));
                        if (u == m1u) andf(rr, (v1 >> 4) & 3, ~(3u << ((v1 & 15) * 2)));
                        ((uint4*)(n32 + v0 * ROWU32))[u] = rr;  // write-through global
                        // column fixups via atomicXor (symmetry gives old value)
#pragma unroll
                        for (int c = 0; c < 4; c++) {
                            unsigned bb = getf(rb, c);
                            if (!bb) continue;
                            unsigned aa = getf(ra, c), vvv = getf(rr, c);
                            int xbase = (u << 6) + (c << 4);
                            unsigned tt = bb;
                            while (tt) {
                                int q = (__ffs(tt) - 1) >> 1;
                                tt &= ~(3u << (q * 2));
                                int x = xbase + q;
                                if (x != v0 && x != v1) {
                                    unsigned dx =
                                        (((aa >> (q*2)) ^ (vvv >> (q*2))) & 3u) << sh0;
                                    if (dx) atomicXor(n32 + x * ROWU32 + wi0, dx);
                                }
                            }
                        }
                    }
                }
            }
            __syncthreads();

            // ---- INVALIDATE fknown: field (a,b) changes only if an endpoint
            // equals a kept survivor v0j (union row write or column-v0j fixup) ----
            if (!dec && fknown) {
                unsigned km = kept;
                while (km) {
                    int j = __ffs(km) - 1; km &= km - 1u;
                    int v0j = (int)(shCand[j] >> 16);
                    if (a == v0j || b == v0j) { fknown = false; break; }
                }
            }
            __syncthreads();
        } else {
            if (head >= E) break;                    // pool empty, stream exhausted
        }

        // ---- COMPACT undecided to low lanes (order-preserving) + REFILL ----
        {
            unsigned long long mU = __ballot(!dec);
            int nU = (int)__popcll(mU);
            // src = index of lane-th set bit of mU (6-step binary search)
            int p = 0;
#pragma unroll
            for (int step = 32; step; step >>= 1) {
                int cand = p + step;
                unsigned long long pref =
                    (cand >= 64) ? ~0ull : ((1ull << cand) - 1ull);
                if ((int)__popcll(mU & pref) <= lane) p = cand;
            }
            unsigned npkv = (unsigned)__shfl((int)pkv, p);
            unsigned nfv  = (unsigned)__shfl((int)fv, p);
            int      nfk  = __shfl((int)fknown, p);
            if (lane < nU) {
                pkv = npkv; fv = nfv; fknown = (nfk != 0); dec = false;
            } else {
                int idx = head + lane - nU;
                if (idx < E) { pkv = pkG[idx]; fknown = false; dec = false; }
                else dec = true;                     // inactive forever
            }
            head += 64 - nU;
        }
    }

    for (int v = lane; v < V; v += 64) {
        uint8_t ao = alive[v];
        aliveG[v] = ao;
        out[V * D + v] = ao ? 1.0f : 0.0f;
    }
    if (lane == 0) { mcountG[0] = mcount; out[V * D + V] = (float)cnt; }
}

// Replay merge forest: per-vertex (root, weight) then scatter-add w*f[v] into out[root].
__launch_bounds__(256)
__global__ void k_apply(const float* __restrict__ f, const unsigned* __restrict__ pairsG,
                        const int* __restrict__ mcountG, float* __restrict__ out) {
    __shared__ unsigned pl[MAXM];
    __shared__ int rootL[256];
    __shared__ float wL[256];
    const int tid = threadIdx.x;
    const int mc = mcountG[0];
    for (int j = tid; j < mc; j += 256) pl[j] = pairsG[j];
    __syncthreads();
    int cur = blockIdx.x * 256 + tid;
    float w = 1.0f;
    for (int j = 0; j < mc; j++) {
        unsigned p = pl[j];
        int v0 = (int)(p >> 16), v1 = (int)(p & 0xFFFFu);
        if (cur == v1) { cur = v0; w *= 0.5f; }
        else if (cur == v0) w *= 0.5f;
    }
    rootL[tid] = cur;
    wL[tid] = w;
    __syncthreads();
    const int sub = tid >> 7;
    const int d = tid & 127;
    for (int s = 0; s < 256; s += 2) {
        int idx = s + sub;
        int vv = blockIdx.x * 256 + idx;
        atomicAdd(&out[rootL[idx] * D + d], wL[idx] * f[vv * D + d]);
    }
}

extern "C" void kernel_launch(void* const* d_in, const int* in_sizes, int n_in,
                              void* d_out, int out_size, void* d_ws, size_t ws_size,
                              hipStream_t stream) {
    (void)in_sizes; (void)n_in; (void)out_size; (void)ws_size;
    const float* features = (const float*)d_in[0];
    const int* edges = (const int*)d_in[1];
    uint8_t* ws = (uint8_t*)d_ws;
    unsigned* n32 = (unsigned*)(ws + WS_N);
    float* pri = (float*)(ws + WS_PRI);
    unsigned long long* keys = (unsigned long long*)(ws + WS_KEYS);
    unsigned* pkG = (unsigned*)(ws + WS_PK);
    unsigned* pairsG = (unsigned*)(ws + WS_PAIRS);
    int* mcountG = (int*)(ws + WS_MCOUNT);
    uint8_t* aliveG = ws + WS_ALIVE;
    float* out = (float*)d_out;

    hipMemsetAsync(n32, 0, (size_t)V * ROWU32 * 4, stream);
    hipMemsetAsync(out, 0, (size_t)V * D * sizeof(float), stream);
    k_pri<<<(V + 255) / 256, 256, 0, stream>>>(features, pri);
    k_scatter<<<(E + 255) / 256, 256, 0, stream>>>(edges, n32);
    k_keys<<<(NPAD + 255) / 256, 256, 0, stream>>>(edges, pri, keys);
    k_sort2<<<2, 1024, 0, stream>>>(keys);
    k_mergepath<<<(E / 64 + 63) / 64, 64, 0, stream>>>(keys, edges, pkG);
    k_collapse<<<1, 64, 0, stream>>>(pkG, n32, pairsG, mcountG, aliveG, out);
    k_apply<<<V / 256, 256, 0, stream>>>(features, pairsG, mcountG, out);
}